// Round 1
// baseline (492.559 us; speedup 1.0000x reference)
//
#include <hip/hip_runtime.h>

// BackgroundNoiseLayer: out[t, n*5+r] = sum_k spikes[t,k] * W[k, n*5+r]
// where W[k, n*5+r] = scatter-add over edges e with cols[e]=k, rows[e]=n of
// weights[e]*tau_syn[e,r].
//
// Sizes: N=50000, K=100, R=5, E=500000, T=250. NCOL = N*R = 250000.
// W is staged f32 in d_ws (100 MB), layout [K][NCOL] so GEMM column loads
// are coalesced across threads.

#define N_NEURONS 50000
#define N_BKG     100
#define N_SYN     5
#define N_EDGES   500000
#define SEQ_T     250
#define NCOL      (N_NEURONS * N_SYN)   // 250000
#define W_ELEMS   ((size_t)N_BKG * NCOL) // 25,000,000 floats = 100 MB

__global__ __launch_bounds__(256) void zero_kernel(float4* __restrict__ w, int n4) {
    int i = blockIdx.x * blockDim.x + threadIdx.x;
    int stride = gridDim.x * blockDim.x;
    float4 z = make_float4(0.f, 0.f, 0.f, 0.f);
    for (; i < n4; i += stride) w[i] = z;
}

__global__ __launch_bounds__(256) void scatter_kernel(
        const float* __restrict__ weights,
        const float* __restrict__ tau,
        const int*   __restrict__ rows,
        const int*   __restrict__ cols,
        float* __restrict__ W2) {
    int e = blockIdx.x * blockDim.x + threadIdx.x;
    if (e >= N_EDGES) return;
    float w = weights[e];
    int row = rows[e];
    int col = cols[e];
    float* base = W2 + (size_t)col * NCOL + (size_t)row * N_SYN;
#pragma unroll
    for (int r = 0; r < N_SYN; ++r) {
        atomicAdd(base + r, w * tau[(size_t)e * N_SYN + r]);
    }
}

// Each thread owns one output column c = n*5+r, accumulating BT timesteps.
// blockIdx.y selects the bt-pass. W loads: coalesced vector loads, reused
// across BT accumulators in registers. Spike loads: wave-uniform address ->
// compiler emits scalar (s_load) reads on the SALU/SMEM pipe, keeping the
// VALU free for FMAs.
template<int BT, int KC>
__global__ __launch_bounds__(256) void gemm_kernel(
        const float* __restrict__ W2,
        const float* __restrict__ spikes,
        float* __restrict__ out) {
    int c = blockIdx.x * 256 + threadIdx.x;
    bool ok = (c < NCOL);
    int cc = ok ? c : 0;
    int g = blockIdx.y;           // bt pass: rows [g*BT, (g+1)*BT)

    float acc[BT];
#pragma unroll
    for (int j = 0; j < BT; ++j) acc[j] = 0.f;

    for (int kc = 0; kc < N_BKG / KC; ++kc) {
        float w[KC];
#pragma unroll
        for (int i = 0; i < KC; ++i)
            w[i] = W2[(size_t)(kc * KC + i) * NCOL + cc];
#pragma unroll
        for (int j = 0; j < BT; ++j) {
#pragma unroll
            for (int i = 0; i < KC; ++i) {
                // uniform address -> scalar load
                float s = spikes[(g * BT + j) * N_BKG + kc * KC + i];
                acc[j] = fmaf(w[i], s, acc[j]);
            }
        }
    }
    if (ok) {
#pragma unroll
        for (int j = 0; j < BT; ++j)
            out[(size_t)(g * BT + j) * NCOL + c] = acc[j];
    }
}

extern "C" void kernel_launch(void* const* d_in, const int* in_sizes, int n_in,
                              void* d_out, int out_size, void* d_ws, size_t ws_size,
                              hipStream_t stream) {
    const float* weights = (const float*)d_in[0];
    const float* tau     = (const float*)d_in[1];
    const float* spikes  = (const float*)d_in[2];
    const int*   rows    = (const int*)d_in[3];
    const int*   cols    = (const int*)d_in[4];
    float* out = (float*)d_out;
    float* W2  = (float*)d_ws;   // 100 MB staging

    // 1) zero W
    int n4 = (int)(W_ELEMS / 4);
    zero_kernel<<<2048, 256, 0, stream>>>((float4*)W2, n4);

    // 2) scatter edges into W
    int eblocks = (N_EDGES + 255) / 256;
    scatter_kernel<<<eblocks, 256, 0, stream>>>(weights, tau, rows, cols, W2);

    // 3) GEMM: out = spikes @ W
    constexpr int BT = 50;
    constexpr int KC = 10;
    dim3 grid((NCOL + 255) / 256, SEQ_T / BT);
    gemm_kernel<BT, KC><<<grid, 256, 0, stream>>>(W2, spikes, out);
}

// Round 2
// 289.956 us; speedup vs baseline: 1.6987x; 1.6987x over previous
//
#include <hip/hip_runtime.h>

// BackgroundNoiseLayer: out[t, n*5+r] = sum_k spikes[t,k] * W[k, n*5+r]
// W[k, c] = scatter-add of weights[e]*tau[e,r] at (cols[e], rows[e]*5+r).
//
// Phase 1: zero f32 W [100][250000] in d_ws (100 MB)
// Phase 2: edge scatter with f32 atomics
// Phase 3: MFMA GEMM out[250,250000] = spikes[250,100] @ W[100,250000]
//          W split in-register into bf16 hi/lo limbs (error ~2^-17 rel),
//          spikes are 0/1 -> bf16-exact. K padded 100->128, M padded 250->256.

#define N_NEURONS 50000
#define N_BKG     100
#define N_SYN     5
#define N_EDGES   500000
#define SEQ_T     250
#define NCOL      (N_NEURONS * N_SYN)    // 250000
#define W_ELEMS   ((size_t)N_BKG * NCOL) // 25M floats = 100 MB

typedef __attribute__((ext_vector_type(8))) short bf16x8;
typedef __attribute__((ext_vector_type(4))) float f32x4;

__global__ __launch_bounds__(256) void zero_kernel(float4* __restrict__ w, int n4) {
    int i = blockIdx.x * blockDim.x + threadIdx.x;
    int stride = gridDim.x * blockDim.x;
    float4 z = make_float4(0.f, 0.f, 0.f, 0.f);
    for (; i < n4; i += stride) w[i] = z;
}

__global__ __launch_bounds__(256) void scatter_kernel(
        const float* __restrict__ weights,
        const float* __restrict__ tau,
        const int*   __restrict__ rows,
        const int*   __restrict__ cols,
        float* __restrict__ W2) {
    int e = blockIdx.x * blockDim.x + threadIdx.x;
    if (e >= N_EDGES) return;
    float w = weights[e];
    int row = rows[e];
    int col = cols[e];
    float* base = W2 + (size_t)col * NCOL + (size_t)row * N_SYN;
#pragma unroll
    for (int r = 0; r < N_SYN; ++r) {
        atomicAdd(base + r, w * tau[(size_t)e * N_SYN + r]);
    }
}

__device__ inline unsigned short bf16_rne(float f) {
    unsigned u = __builtin_bit_cast(unsigned, f);
    u += 0x7FFFu + ((u >> 16) & 1u);
    return (unsigned short)(u >> 16);
}

// Block = 4 waves, covers 80 output columns x 256 (padded) t-rows.
// wave w handles m-tiles 4w..4w+3 (each 16 t-rows) x 5 n-tiles (16 cols).
// A frag: row = l&15, k = (l>>4)*8+i ; B frag: col = l&15, same k.
// D frag: col = l&15, row = (l>>4)*4 + reg (m89-verified).
__global__ __launch_bounds__(256) void gemm_mfma_kernel(
        const float* __restrict__ W2,
        const float* __restrict__ spikes,
        float* __restrict__ out) {
    const int l  = threadIdx.x & 63;
    const int wv = threadIdx.x >> 6;     // wave 0..3
    const int lc = l & 15;               // A-row / B-col / D-col within tile
    const int lq = l >> 4;               // quarter-wave 0..3
    const int cb = blockIdx.x * 80;      // column base (3125*80 = 250000 exact)

    f32x4 acc[4][5];
#pragma unroll
    for (int q = 0; q < 4; ++q)
#pragma unroll
        for (int nt = 0; nt < 5; ++nt)
            acc[q][nt] = (f32x4){0.f, 0.f, 0.f, 0.f};

#pragma unroll
    for (int kk = 0; kk < 128; kk += 32) {
        // ---- A fragments (spikes, 0/1 -> bf16 exact via truncation) ----
        bf16x8 a[4];
#pragma unroll
        for (int q = 0; q < 4; ++q) {
            int t = (wv * 4 + q) * 16 + lc;
            int tt = t < SEQ_T ? t : (SEQ_T - 1);   // clamp; stores masked later
            int kbase = kk + lq * 8;
            float4 a0 = make_float4(0.f, 0.f, 0.f, 0.f);
            float4 a1 = make_float4(0.f, 0.f, 0.f, 0.f);
            const float* sp = spikes + (size_t)tt * N_BKG + kbase;
            if (kbase + 8 <= N_BKG) {               // full 8 valid
                a0 = *(const float4*)sp;
                a1 = *(const float4*)(sp + 4);
            } else if (kbase + 4 <= N_BKG) {        // kk=96, lq=0: k 96..99
                a0 = *(const float4*)sp;
            }                                       // else all-zero pad
            a[q][0] = (short)(__builtin_bit_cast(unsigned, a0.x) >> 16);
            a[q][1] = (short)(__builtin_bit_cast(unsigned, a0.y) >> 16);
            a[q][2] = (short)(__builtin_bit_cast(unsigned, a0.z) >> 16);
            a[q][3] = (short)(__builtin_bit_cast(unsigned, a0.w) >> 16);
            a[q][4] = (short)(__builtin_bit_cast(unsigned, a1.x) >> 16);
            a[q][5] = (short)(__builtin_bit_cast(unsigned, a1.y) >> 16);
            a[q][6] = (short)(__builtin_bit_cast(unsigned, a1.z) >> 16);
            a[q][7] = (short)(__builtin_bit_cast(unsigned, a1.w) >> 16);
        }
        // ---- B fragments (W hi/lo split) + MFMA ----
#pragma unroll
        for (int nt = 0; nt < 5; ++nt) {
            int c = cb + nt * 16 + lc;
            bf16x8 bhi, blo;
#pragma unroll
            for (int i = 0; i < 8; ++i) {
                int k = kk + lq * 8 + i;
                int ke = k < N_BKG ? k : (N_BKG - 1);   // clamp addr; A=0 kills it
                float v = W2[(size_t)ke * NCOL + c];
                unsigned short h = bf16_rne(v);
                float hf = __builtin_bit_cast(float, (unsigned)h << 16);
                unsigned short lo = bf16_rne(v - hf);
                bhi[i] = (short)h;
                blo[i] = (short)lo;
            }
#pragma unroll
            for (int q = 0; q < 4; ++q) {
                acc[q][nt] = __builtin_amdgcn_mfma_f32_16x16x32_bf16(
                                 a[q], bhi, acc[q][nt], 0, 0, 0);
                acc[q][nt] = __builtin_amdgcn_mfma_f32_16x16x32_bf16(
                                 a[q], blo, acc[q][nt], 0, 0, 0);
            }
        }
    }

    // ---- store: D col = lc, row = lq*4 + r within each m-tile ----
#pragma unroll
    for (int q = 0; q < 4; ++q) {
        int tbase = (wv * 4 + q) * 16 + lq * 4;
#pragma unroll
        for (int nt = 0; nt < 5; ++nt) {
            int c = cb + nt * 16 + lc;
#pragma unroll
            for (int r = 0; r < 4; ++r) {
                int t = tbase + r;
                if (t < SEQ_T)
                    out[(size_t)t * NCOL + c] = acc[q][nt][r];
            }
        }
    }
}

extern "C" void kernel_launch(void* const* d_in, const int* in_sizes, int n_in,
                              void* d_out, int out_size, void* d_ws, size_t ws_size,
                              hipStream_t stream) {
    const float* weights = (const float*)d_in[0];
    const float* tau     = (const float*)d_in[1];
    const float* spikes  = (const float*)d_in[2];
    const int*   rows    = (const int*)d_in[3];
    const int*   cols    = (const int*)d_in[4];
    float* out = (float*)d_out;
    float* W2  = (float*)d_ws;   // 100 MB f32 staging

    int n4 = (int)(W_ELEMS / 4);
    zero_kernel<<<2048, 256, 0, stream>>>((float4*)W2, n4);

    int eblocks = (N_EDGES + 255) / 256;
    scatter_kernel<<<eblocks, 256, 0, stream>>>(weights, tau, rows, cols, W2);

    gemm_mfma_kernel<<<3125, 256, 0, stream>>>(W2, spikes, out);
}

// Round 3
// 152.007 us; speedup vs baseline: 3.2404x; 1.9075x over previous
//
#include <hip/hip_runtime.h>

// BackgroundNoiseLayer, fully fused plan:
//   out[t, n*5+r] = sum_k spikes[t,k] * W[k, n*5+r],
//   W[k, n*5+r]   = sum over edges e (cols[e]=k, rows[e]=n) of weights[e]*tau[e,r]
//
// Key observation: a GEMM block owning 80 output columns = 16 neurons x 5
// receptors needs only the W slice [100 k][80 cols] = 32 KB -> build it in
// LDS directly from an edge bucket, never materializing W in global memory.
//
// K0: zero bin counters; build bf16 spike table spb[256][128] (zero-padded)
// K1: bucket edges by neuron-range (bin = row/16), record = {col,noff,w*tau[0..4]}
// K2: per block: LDS slice accumulate (ds_add_f32) -> MFMA GEMM (bf16 hi/lo)

#define N_NEURONS 50000
#define N_BKG     100
#define N_SYN     5
#define N_EDGES   500000
#define SEQ_T     250
#define NCOL      (N_NEURONS * N_SYN)   // 250000
#define RPB       16                    // neurons per bin/block
#define NBINS     (N_NEURONS / RPB)     // 3125
#define CAP       512                   // record capacity per bin (mean 160)
#define REC_U32   8                     // 32 B records
#define KPAD      128                   // K padded 100 -> 128 (zeros)
#define CPAD      81                    // 80 cols + 1 pad: 2-way LDS aliasing (free)

// d_ws layout
#define WS_COUNT_OFF 0                       // NBINS u32
#define WS_SPB_OFF   65536                   // 256*128 bf16 = 64 KB
#define WS_REC_OFF   131072                  // NBINS*CAP*32 B = 51.2 MB

typedef __attribute__((ext_vector_type(8))) short bf16x8;
typedef __attribute__((ext_vector_type(4))) float f32x4;

__device__ inline unsigned short bf16_rne(float f) {
    unsigned u = __builtin_bit_cast(unsigned, f);
    u += 0x7FFFu + ((u >> 16) & 1u);
    return (unsigned short)(u >> 16);
}

// K0: zero counters + build padded bf16 spike table. 128 blocks x 256.
__global__ __launch_bounds__(256) void init_kernel(
        const float* __restrict__ spikes,
        unsigned* __restrict__ count,
        unsigned short* __restrict__ spb) {
    int i = blockIdx.x * 256 + threadIdx.x;      // 0..32767
    if (i < NBINS) count[i] = 0;
    int t = i >> 7, k = i & 127;                 // spb[t][k], 256 x 128
    unsigned short v = 0;
    if (t < SEQ_T && k < N_BKG) {
        float s = spikes[t * N_BKG + k];         // 0.0f or 1.0f -> bf16 exact
        v = (unsigned short)(__builtin_bit_cast(unsigned, s) >> 16);
    }
    spb[i] = v;
}

// K1: bucket-append edges. One thread per edge.
__global__ __launch_bounds__(256) void bucket_kernel(
        const float* __restrict__ weights,
        const float* __restrict__ tau,
        const int*   __restrict__ rows,
        const int*   __restrict__ cols,
        unsigned* __restrict__ count,
        unsigned* __restrict__ rec) {
    int e = blockIdx.x * 256 + threadIdx.x;
    if (e >= N_EDGES) return;
    int row = rows[e];
    int col = cols[e];
    float w = weights[e];
    const float* tp = tau + (size_t)e * N_SYN;
    int bin = row >> 4;                          // row / RPB
    unsigned slot = atomicAdd(&count[bin], 1u);
    if (slot >= CAP) return;                     // statistically impossible
    unsigned* rp = rec + ((size_t)bin * CAP + slot) * REC_U32;
    uint4 r0, r1;
    r0.x = ((unsigned)col << 4) | (unsigned)(row & 15);
    r0.y = __builtin_bit_cast(unsigned, w * tp[0]);
    r0.z = __builtin_bit_cast(unsigned, w * tp[1]);
    r0.w = __builtin_bit_cast(unsigned, w * tp[2]);
    r1.x = __builtin_bit_cast(unsigned, w * tp[3]);
    r1.y = __builtin_bit_cast(unsigned, w * tp[4]);
    r1.z = 0; r1.w = 0;
    *(uint4*)(rp)     = r0;
    *(uint4*)(rp + 4) = r1;
}

// K2: fused LDS scatter + MFMA GEMM. 3125 blocks x 256 (4 waves).
// Block b: neurons [16b,16b+16) -> output cols [80b, 80b+80).
// Wave wv handles m-tiles 4wv..4wv+3 (16 t-rows each) x 5 n-tiles.
// A frag: row=l&15, k=(l>>4)*8+i ; B frag: col=l&15, same k.
// D frag: col=l&15, row=(l>>4)*4+reg (m89-verified mapping).
__global__ __launch_bounds__(256) void fused_kernel(
        const unsigned* __restrict__ count,
        const unsigned* __restrict__ rec,
        const unsigned short* __restrict__ spb,
        float* __restrict__ out) {
    __shared__ float slice[KPAD * CPAD];         // 41.5 KB

    const int tid = threadIdx.x;
    const int b   = blockIdx.x;

    // zero slice (incl. k=100..127 pad rows -> no clamping in GEMM)
    for (int i = tid; i < KPAD * CPAD; i += 256) slice[i] = 0.f;
    __syncthreads();

    // accumulate this block's edge records into the LDS slice
    unsigned cnt = count[b];
    if (cnt > CAP) cnt = CAP;
    for (unsigned i = tid; i < cnt; i += 256) {
        const unsigned* rp = rec + ((size_t)b * CAP + i) * REC_U32;
        uint4 r0 = *(const uint4*)(rp);
        uint4 r1 = *(const uint4*)(rp + 4);
        int k    = (int)(r0.x >> 4);
        int noff = (int)(r0.x & 15u);
        float* base = &slice[k * CPAD + noff * N_SYN];
        atomicAdd(base + 0, __builtin_bit_cast(float, r0.y));
        atomicAdd(base + 1, __builtin_bit_cast(float, r0.z));
        atomicAdd(base + 2, __builtin_bit_cast(float, r0.w));
        atomicAdd(base + 3, __builtin_bit_cast(float, r1.x));
        atomicAdd(base + 4, __builtin_bit_cast(float, r1.y));
    }
    __syncthreads();

    // ---- MFMA GEMM ----
    const int l  = tid & 63;
    const int wv = tid >> 6;
    const int lc = l & 15;
    const int lq = l >> 4;
    const int cb = b * 80;

    f32x4 acc[4][5];
#pragma unroll
    for (int q = 0; q < 4; ++q)
#pragma unroll
        for (int nt = 0; nt < 5; ++nt)
            acc[q][nt] = (f32x4){0.f, 0.f, 0.f, 0.f};

#pragma unroll
    for (int kk = 0; kk < KPAD; kk += 32) {
        bf16x8 a[4];
#pragma unroll
        for (int q = 0; q < 4; ++q) {
            int t = (wv * 4 + q) * 16 + lc;              // < 256, pad rows are 0
            a[q] = *(const bf16x8*)(spb + (size_t)t * KPAD + kk + lq * 8);
        }
#pragma unroll
        for (int nt = 0; nt < 5; ++nt) {
            bf16x8 bhi, blo;
#pragma unroll
            for (int i = 0; i < 8; ++i) {
                float v = slice[(kk + lq * 8 + i) * CPAD + nt * 16 + lc];
                unsigned short h = bf16_rne(v);
                float hf = __builtin_bit_cast(float, (unsigned)h << 16);
                bhi[i] = (short)h;
                blo[i] = (short)bf16_rne(v - hf);
            }
#pragma unroll
            for (int q = 0; q < 4; ++q) {
                acc[q][nt] = __builtin_amdgcn_mfma_f32_16x16x32_bf16(
                                 a[q], bhi, acc[q][nt], 0, 0, 0);
                acc[q][nt] = __builtin_amdgcn_mfma_f32_16x16x32_bf16(
                                 a[q], blo, acc[q][nt], 0, 0, 0);
            }
        }
    }

#pragma unroll
    for (int q = 0; q < 4; ++q) {
        int tbase = (wv * 4 + q) * 16 + lq * 4;
#pragma unroll
        for (int nt = 0; nt < 5; ++nt) {
            int c = cb + nt * 16 + lc;
#pragma unroll
            for (int r = 0; r < 4; ++r) {
                int t = tbase + r;
                if (t < SEQ_T)
                    out[(size_t)t * NCOL + c] = acc[q][nt][r];
            }
        }
    }
}

extern "C" void kernel_launch(void* const* d_in, const int* in_sizes, int n_in,
                              void* d_out, int out_size, void* d_ws, size_t ws_size,
                              hipStream_t stream) {
    const float* weights = (const float*)d_in[0];
    const float* tau     = (const float*)d_in[1];
    const float* spikes  = (const float*)d_in[2];
    const int*   rows    = (const int*)d_in[3];
    const int*   cols    = (const int*)d_in[4];
    float* out = (float*)d_out;

    char* ws = (char*)d_ws;
    unsigned*       count = (unsigned*)(ws + WS_COUNT_OFF);
    unsigned short* spb   = (unsigned short*)(ws + WS_SPB_OFF);
    unsigned*       rec   = (unsigned*)(ws + WS_REC_OFF);

    init_kernel<<<128, 256, 0, stream>>>(spikes, count, spb);

    int eblocks = (N_EDGES + 255) / 256;
    bucket_kernel<<<eblocks, 256, 0, stream>>>(weights, tau, rows, cols, count, rec);

    fused_kernel<<<NBINS, 256, 0, stream>>>(count, rec, spb, out);
}

// Round 4
// 145.985 us; speedup vs baseline: 3.3740x; 1.0413x over previous
//
#include <hip/hip_runtime.h>

// BackgroundNoiseLayer, fused plan:
//   out[t, n*5+r] = sum_k spikes[t,k] * W[k, n*5+r],
//   W[k, n*5+r]   = sum over edges e (cols[e]=k, rows[e]=n) of weights[e]*tau[e,r]
//
// K0: zero bin counters; build bf16 spike table spb[256][128] (zero-padded)
// K1: bucket edges by neuron-range (bin = row/16), record = {col,noff,w*tau[0..4]}
// K2: per block: LDS f32 slice scatter (ds_add) -> ONE bf16 hi/lo conversion
//     pass into transposed XOR-swizzled LDS -> MFMA GEMM with ds_read_b128
//     B-fragments. W never exists in global memory.

#define N_NEURONS 50000
#define N_BKG     100
#define N_SYN     5
#define N_EDGES   500000
#define SEQ_T     250
#define NCOL      (N_NEURONS * N_SYN)   // 250000
#define RPB       16                    // neurons per bin/block
#define NBINS     (N_NEURONS / RPB)     // 3125
#define CAP       512                   // record capacity per bin (mean 160)
#define REC_U32   8                     // 32 B record stride
#define KPAD      128                   // K padded 100 -> 128 (zeros)
#define CPAD      81                    // f32 slice leading-dim pad
#define BCOLS     80                    // output cols per block
#define LO_OFF    20480                 // byte offset of lo-limb region in LDS

// d_ws layout
#define WS_COUNT_OFF 0                  // NBINS u32
#define WS_SPB_OFF   65536              // 256*128 bf16 = 64 KB
#define WS_REC_OFF   131072             // NBINS*CAP*32 B = 51.2 MB

typedef __attribute__((ext_vector_type(8))) short bf16x8;
typedef __attribute__((ext_vector_type(4))) float f32x4;

__device__ inline unsigned short bf16_rne(float f) {
    unsigned u = __builtin_bit_cast(unsigned, f);
    u += 0x7FFFu + ((u >> 16) & 1u);
    return (unsigned short)(u >> 16);
}

// K0: zero counters + build padded bf16 spike table. 128 blocks x 256.
__global__ __launch_bounds__(256) void init_kernel(
        const float* __restrict__ spikes,
        unsigned* __restrict__ count,
        unsigned short* __restrict__ spb) {
    int i = blockIdx.x * 256 + threadIdx.x;      // 0..32767
    if (i < NBINS) count[i] = 0;
    int t = i >> 7, k = i & 127;                 // spb[t][k], 256 x 128
    unsigned short v = 0;
    if (t < SEQ_T && k < N_BKG) {
        float s = spikes[t * N_BKG + k];         // 0.0f / 1.0f -> bf16 exact
        v = (unsigned short)(__builtin_bit_cast(unsigned, s) >> 16);
    }
    spb[i] = v;
}

// K1: bucket-append edges. One thread per edge.
__global__ __launch_bounds__(256) void bucket_kernel(
        const float* __restrict__ weights,
        const float* __restrict__ tau,
        const int*   __restrict__ rows,
        const int*   __restrict__ cols,
        unsigned* __restrict__ count,
        unsigned* __restrict__ rec) {
    int e = blockIdx.x * 256 + threadIdx.x;
    if (e >= N_EDGES) return;
    int row = rows[e];
    int col = cols[e];
    float w = weights[e];
    const float* tp = tau + (size_t)e * N_SYN;
    int bin = row >> 4;                          // row / RPB
    unsigned slot = atomicAdd(&count[bin], 1u);
    if (slot >= CAP) return;                     // statistically impossible
    unsigned* rp = rec + ((size_t)bin * CAP + slot) * REC_U32;
    uint4 r0;
    uint2 r1;
    r0.x = ((unsigned)col << 4) | (unsigned)(row & 15);
    r0.y = __builtin_bit_cast(unsigned, w * tp[0]);
    r0.z = __builtin_bit_cast(unsigned, w * tp[1]);
    r0.w = __builtin_bit_cast(unsigned, w * tp[2]);
    r1.x = __builtin_bit_cast(unsigned, w * tp[3]);
    r1.y = __builtin_bit_cast(unsigned, w * tp[4]);
    *(uint4*)(rp)     = r0;
    *(uint2*)(rp + 4) = r1;
}

// K2: fused LDS scatter + bf16 conversion + MFMA GEMM. 3125 blocks x 256.
// Block b: neurons [16b,16b+16) -> output cols [80b, 80b+80).
// A frag: row=l&15, k=(l>>4)*8+i ; B frag: col=l&15, same k.
// D frag: col=l&15, row=(l>>4)*4+reg (layout verified in rounds 2-3).
__global__ __launch_bounds__(256) void fused_kernel(
        const unsigned* __restrict__ count,
        const unsigned* __restrict__ rec,
        const unsigned short* __restrict__ spb,
        float* __restrict__ out) {
    __shared__ float slice[KPAD * CPAD];         // 41472 B, reused for bf16 limbs

    const int tid = threadIdx.x;
    const int b   = blockIdx.x;

    // ---- zero f32 slice (incl. k=100..127 pad rows) ----
    for (int i = tid; i < KPAD * CPAD; i += 256) slice[i] = 0.f;
    __syncthreads();

    // ---- scatter this block's edge records into the f32 slice ----
    unsigned cnt = count[b];
    if (cnt > CAP) cnt = CAP;
    for (unsigned i = tid; i < cnt; i += 256) {
        const unsigned* rp = rec + ((size_t)b * CAP + i) * REC_U32;
        uint4 r0 = *(const uint4*)(rp);
        uint2 r1 = *(const uint2*)(rp + 4);
        int k    = (int)(r0.x >> 4);
        int noff = (int)(r0.x & 15u);
        float* base = &slice[k * CPAD + noff * N_SYN];
        atomicAdd(base + 0, __builtin_bit_cast(float, r0.y));
        atomicAdd(base + 1, __builtin_bit_cast(float, r0.z));
        atomicAdd(base + 2, __builtin_bit_cast(float, r0.w));
        atomicAdd(base + 3, __builtin_bit_cast(float, r1.x));
        atomicAdd(base + 4, __builtin_bit_cast(float, r1.y));
    }
    __syncthreads();

    // ---- convert slice ONCE to bf16 hi/lo, transposed [c][k], XOR-swizzled.
    // 1280 chunks of (c, 8 consecutive k); c-major so lane reads are
    // conflict-free. Held in regs across the barrier, then written in-place.
    bf16x8 hi[5], lo[5];
    unsigned boff[5];
#pragma unroll
    for (int j = 0; j < 5; ++j) {
        int m  = tid + j * 256;                  // 0..1279
        int c  = m % BCOLS;
        int kb = m / BCOLS;                      // 0..15
#pragma unroll
        for (int i = 0; i < 8; ++i) {
            float v = slice[(kb * 8 + i) * CPAD + c];
            unsigned short h = bf16_rne(v);
            float hf = __builtin_bit_cast(float, (unsigned)h << 16);
            hi[j][i] = (short)h;
            lo[j][i] = (short)bf16_rne(v - hf);
        }
        boff[j] = (unsigned)((c * 256 + kb * 16) ^ ((c & 7) << 4));
    }
    __syncthreads();
#pragma unroll
    for (int j = 0; j < 5; ++j) {
        *(bf16x8*)((char*)slice + boff[j])          = hi[j];
        *(bf16x8*)((char*)slice + LO_OFF + boff[j]) = lo[j];
    }
    __syncthreads();

    // ---- MFMA GEMM ----
    const int l  = tid & 63;
    const int wv = tid >> 6;
    const int lc = l & 15;
    const int lq = l >> 4;
    const int cb = b * BCOLS;

    f32x4 acc[4][5];
#pragma unroll
    for (int q = 0; q < 4; ++q)
#pragma unroll
        for (int nt = 0; nt < 5; ++nt)
            acc[q][nt] = (f32x4){0.f, 0.f, 0.f, 0.f};

#pragma unroll
    for (int kk = 0; kk < KPAD; kk += 32) {
        bf16x8 a[4];
#pragma unroll
        for (int q = 0; q < 4; ++q) {
            int t = (wv * 4 + q) * 16 + lc;              // < 256, pad rows are 0
            a[q] = *(const bf16x8*)(spb + (size_t)t * KPAD + kk + lq * 8);
        }
#pragma unroll
        for (int nt = 0; nt < 5; ++nt) {
            int c = nt * 16 + lc;
            unsigned boffr = (unsigned)((c * 256 + kk * 2 + lq * 16) ^ ((c & 7) << 4));
            bf16x8 bhi = *(const bf16x8*)((const char*)slice + boffr);
            bf16x8 blo = *(const bf16x8*)((const char*)slice + LO_OFF + boffr);
#pragma unroll
            for (int q = 0; q < 4; ++q) {
                acc[q][nt] = __builtin_amdgcn_mfma_f32_16x16x32_bf16(
                                 a[q], bhi, acc[q][nt], 0, 0, 0);
                acc[q][nt] = __builtin_amdgcn_mfma_f32_16x16x32_bf16(
                                 a[q], blo, acc[q][nt], 0, 0, 0);
            }
        }
    }

    // ---- store: D col = lc, row = lq*4 + r within each m-tile ----
#pragma unroll
    for (int q = 0; q < 4; ++q) {
        int tbase = (wv * 4 + q) * 16 + lq * 4;
#pragma unroll
        for (int nt = 0; nt < 5; ++nt) {
            int c = cb + nt * 16 + lc;
#pragma unroll
            for (int r = 0; r < 4; ++r) {
                int t = tbase + r;
                if (t < SEQ_T)
                    out[(size_t)t * NCOL + c] = acc[q][nt][r];
            }
        }
    }
}

extern "C" void kernel_launch(void* const* d_in, const int* in_sizes, int n_in,
                              void* d_out, int out_size, void* d_ws, size_t ws_size,
                              hipStream_t stream) {
    const float* weights = (const float*)d_in[0];
    const float* tau     = (const float*)d_in[1];
    const float* spikes  = (const float*)d_in[2];
    const int*   rows    = (const int*)d_in[3];
    const int*   cols    = (const int*)d_in[4];
    float* out = (float*)d_out;

    char* ws = (char*)d_ws;
    unsigned*       count = (unsigned*)(ws + WS_COUNT_OFF);
    unsigned short* spb   = (unsigned short*)(ws + WS_SPB_OFF);
    unsigned*       rec   = (unsigned*)(ws + WS_REC_OFF);

    init_kernel<<<128, 256, 0, stream>>>(spikes, count, spb);

    int eblocks = (N_EDGES + 255) / 256;
    bucket_kernel<<<eblocks, 256, 0, stream>>>(weights, tau, rows, cols, count, rec);

    fused_kernel<<<NBINS, 256, 0, stream>>>(count, rec, spb, out);
}